// Round 5
// baseline (281.165 us; speedup 1.0000x reference)
//
#include <hip/hip_runtime.h>
#include <cstdint>
#include <cstddef>

typedef __bf16 bf16;
typedef __bf16 bf16x8 __attribute__((ext_vector_type(8)));
typedef __bf16 bf16x4 __attribute__((ext_vector_type(4)));
typedef short  s16x4  __attribute__((ext_vector_type(4)));
typedef float  f32x4  __attribute__((ext_vector_type(4)));

#define MFMA16(a, b, c) __builtin_amdgcn_mfma_f32_16x16x32_bf16((a), (b), (c), 0, 0, 0)

#if __has_builtin(__builtin_amdgcn_mfma_f32_16x16x16bf16_1k)
#define HAVE_K16 1
#else
#define HAVE_K16 0
#endif

#if __has_builtin(__builtin_amdgcn_exp2f)
#define EXP2(x) __builtin_amdgcn_exp2f(x)
#else
static __device__ __forceinline__ float exp2_asm(float x) {
    float r;
    asm("v_exp_f32 %0, %1" : "=v"(r) : "v"(x));
    return r;
}
#define EXP2(x) exp2_asm(x)
#endif

// Problem constants
constexpr int Bsz = 4;
constexpr int T   = 2048;
constexpr int Cd  = 1024;
constexpr int Hn  = 16;
constexpr int Mrows = Bsz * T;          // 8192
constexpr int QKV_LD = 3 * Cd;          // 3072

// softmax scale folded into Q at GEMM1 epilogue: 1/sqrt(64) * log2(e)
constexpr float QSCALE = 0.125f * 1.4426950408889634f;

// ---------------------------------------------------------------------------
// Fused prep: x fp32->bf16 cvt  +  W_attn transpose  +  W_proj transpose.
// One launch instead of three (saves ~2 inter-kernel gaps).
// Block ranges: [0,4096) cvt, [4096,7168) W_attn, [7168,8192) W_proj.
// ---------------------------------------------------------------------------
__global__ __launch_bounds__(256) void prep(const float* __restrict__ x,
                                            const float* __restrict__ W_attn,
                                            const float* __restrict__ W_proj,
                                            bf16* __restrict__ xb,
                                            bf16* __restrict__ Wat,
                                            bf16* __restrict__ Wpt) {
    __shared__ float tile[32][33];
    const int bid = blockIdx.x;
    const int tid = threadIdx.x;
    if (bid < 4096) {                       // ---- cvt x -> xb (8 elems/thread)
        const int i = (bid * 256 + tid) * 8;
        float4 a = *(const float4*)(x + i);
        float4 b = *(const float4*)(x + i + 4);
        bf16x8 o;
        o[0] = (bf16)a.x; o[1] = (bf16)a.y; o[2] = (bf16)a.z; o[3] = (bf16)a.w;
        o[4] = (bf16)b.x; o[5] = (bf16)b.y; o[6] = (bf16)b.z; o[7] = (bf16)b.w;
        *(bf16x8*)(xb + i) = o;
        return;
    }
    const float* W; bf16* Wt; int NDIM, bx, by;
    if (bid < 4096 + 3072) {
        const int r = bid - 4096;
        W = W_attn; Wt = Wat; NDIM = QKV_LD; bx = r % 96; by = r / 96;
    } else {
        const int r = bid - 7168;
        W = W_proj; Wt = Wpt; NDIM = Cd; bx = r & 31; by = r >> 5;
    }
    const int k0 = by * 32, n0 = bx * 32;
    const int tx = tid & 31, ty = tid >> 5;
    #pragma unroll
    for (int r = 0; r < 32; r += 8)
        tile[r + ty][tx] = W[(size_t)(k0 + r + ty) * NDIM + n0 + tx];
    __syncthreads();
    #pragma unroll
    for (int r = 0; r < 32; r += 8)
        Wt[(size_t)(n0 + r + ty) * Cd + k0 + tx] = (bf16)tile[tx][r + ty];
}

// ---------------------------------------------------------------------------
// 256x256-tile 8-wave bf16 GEMM, v2 deep-pipelined schedule (round-4, kept).
// 24 ds_read_b128/K-tile, 4 barriers/K-tile, counted vmcnt (never 0 in loop),
// granule-XOR swizzle, XCD-aware remap. FIFO audit in round-4 notes.
// ---------------------------------------------------------------------------
template <int N, bool OUT_BF16>
__global__ __launch_bounds__(512, 2) void gemm256(const bf16* __restrict__ A,
                                                  const bf16* __restrict__ Bt,
                                                  const float* __restrict__ bias,
                                                  void* __restrict__ outp,
                                                  float oscale, int oscale_n) {
    constexpr int K  = 1024;
    constexpr int KT = K / 64;          // 16 K-tiles
    __shared__ __align__(16) bf16 lds[65536];   // A: [0,32768), B: [32768,65536)

    const int tid  = threadIdx.x;
    const int wv   = tid >> 6;          // 0..7
    const int lane = tid & 63;
    const int wm   = wv >> 2;           // 0..1 : M-wave
    const int wn   = wv & 3;            // 0..3 : N-wave
    const int quad = lane >> 4, c16 = lane & 15;
    const int sw   = c16 & 7;

    const int lin = (int)blockIdx.x;
    const int x8  = lin & 7;
    const int q   = lin >> 3;
    const int m0  = (x8 + 8 * (q & 3)) * 256;
    const int n0  = (q >> 2) * 256;

    auto stage = [&](int kt, int isB, int h) {
        if (kt >= KT) return;
        const int db = kt & 1;
        #pragma unroll
        for (int r = 0; r < 2; ++r) {
            const int idx  = r * 512 + tid;
            const int slot = idx >> 3;
            const int gq   = idx & 7;
            const int kg   = kt * 64 + ((gq ^ (slot & 7)) << 3);
            const bf16* src;
            if (isB) {
                const int col = ((slot >> 5) << 6) + h * 32 + (slot & 31);
                src = Bt + (size_t)(n0 + col) * K + kg;
            } else {
                const int row = ((slot >> 6) << 7) + h * 64 + (slot & 63);
                src = A + (size_t)(m0 + row) * K + kg;
            }
            bf16* dst = &lds[(isB ? 32768 : 0) + db * 16384 + h * 8192 + (r * 8 + wv) * 512];
            __builtin_amdgcn_global_load_lds(
                (const __attribute__((address_space(1))) void*)src,
                (__attribute__((address_space(3))) void*)dst, 16, 0, 0);
        }
    };

    f32x4 acc[8][4] = {};
    bf16x8 af[4][2], b0[2][2], b1[2][2];

#define READ_A(QM, DB)                                                           \
    _Pragma("unroll") for (int mq = 0; mq < 4; ++mq)                             \
        _Pragma("unroll") for (int ks = 0; ks < 2; ++ks)                         \
            af[mq][ks] = *(const bf16x8*)&lds[(DB) * 16384 + (QM) * 8192 +       \
                (wm * 64 + mq * 16 + c16) * 64 + (((ks * 4 + quad) ^ sw) << 3)];
#define READ_B(DST, QN, DB)                                                      \
    _Pragma("unroll") for (int nq = 0; nq < 2; ++nq)                             \
        _Pragma("unroll") for (int ks = 0; ks < 2; ++ks)                         \
            DST[nq][ks] = *(const bf16x8*)&lds[32768 + (DB) * 16384 + (QN) * 8192 + \
                (wn * 32 + nq * 16 + c16) * 64 + (((ks * 4 + quad) ^ sw) << 3)];
#define MFMA_Q(QM, QN, BREG)                                                     \
    __builtin_amdgcn_s_setprio(1);                                               \
    _Pragma("unroll") for (int mq = 0; mq < 4; ++mq)                             \
        _Pragma("unroll") for (int nq = 0; nq < 2; ++nq)                         \
            _Pragma("unroll") for (int ks = 0; ks < 2; ++ks)                     \
                acc[(QM) * 4 + mq][(QN) * 2 + nq] =                              \
                    MFMA16(af[mq][ks], BREG[nq][ks],                             \
                           acc[(QM) * 4 + mq][(QN) * 2 + nq]);                   \
    __builtin_amdgcn_s_setprio(0);
#define VMBAR(NSTR)                                                              \
    asm volatile("s_waitcnt vmcnt(" NSTR ")" ::: "memory");                      \
    __builtin_amdgcn_s_barrier();

    stage(0, 0, 0); stage(0, 1, 0); stage(0, 1, 1); stage(0, 0, 1);
    VMBAR("4")

    #pragma unroll 1
    for (int u = 0; u < KT - 1; ++u) {
        const int db = u & 1;
        const int kn = u + 1;
        READ_A(0, db)
        READ_B(b0, 0, db)
        stage(kn, 0, 0); stage(kn, 1, 0);
        MFMA_Q(0, 0, b0)
        VMBAR("6")
        READ_B(b1, 1, db)
        stage(kn, 1, 1);
        MFMA_Q(0, 1, b1)
        VMBAR("6")
        READ_A(1, db)
        stage(kn, 0, 1);
        MFMA_Q(1, 0, b0)
        __builtin_amdgcn_s_barrier();
        MFMA_Q(1, 1, b1)
        VMBAR("4")
    }

    READ_A(0, 1)
    READ_B(b0, 0, 1)
    MFMA_Q(0, 0, b0)
    VMBAR("2")
    READ_B(b1, 1, 1)
    MFMA_Q(0, 1, b1)
    VMBAR("0")
    READ_A(1, 1)
    MFMA_Q(1, 0, b0)
    MFMA_Q(1, 1, b1)

#undef READ_A
#undef READ_B
#undef MFMA_Q
#undef VMBAR

    #pragma unroll
    for (int nb = 0; nb < 4; ++nb) {
        const int n = n0 + wn * 64 + nb * 16 + c16;
        const float bv = bias[n];
        const float sc = (n < oscale_n) ? oscale : 1.0f;
        #pragma unroll
        for (int mb = 0; mb < 8; ++mb) {
            const int mbase = m0 + wm * 128 + mb * 16 + quad * 4;
            #pragma unroll
            for (int r = 0; r < 4; ++r) {
                float val = (acc[mb][nb][r] + bv) * sc;
                if (OUT_BF16)
                    ((bf16*)outp)[(size_t)(mbase + r) * N + n] = (bf16)val;
                else
                    ((float*)outp)[(size_t)(mbase + r) * N + n] = val;
            }
        }
    }
}

// ---------------------------------------------------------------------------
// bf16 MFMA GEMM, 128^2 (m97 pattern) — GEMM2 (N=1024). Granule-XOR swizzle
// + XCD remap.
// ---------------------------------------------------------------------------
template <int N, bool OUT_BF16>
__global__ __launch_bounds__(256) void gemm_bf16(const bf16* __restrict__ A,
                                                 const bf16* __restrict__ Bt,
                                                 const float* __restrict__ bias,
                                                 void* __restrict__ outp,
                                                 float oscale, int oscale_n) {
    constexpr int K = 1024;
    __shared__ __align__(16) bf16 As[128 * 64];
    __shared__ __align__(16) bf16 Bs[128 * 64];

    const int tid  = threadIdx.x;
    const int w    = tid >> 6;
    const int lane = tid & 63;
    const int wm   = w & 1, wn = w >> 1;
    const int quad = lane >> 4, c16 = lane & 15;

    const int lin = (int)(blockIdx.y * gridDim.x + blockIdx.x);
    const int x8  = lin & 7;
    const int q   = lin >> 3;
    const int m0  = (x8 + 8 * (q & 7)) * 128;
    const int n0  = (q >> 3) * 128;

    const int srow = lane >> 3;                      // 0..7
    const int scol = ((lane & 7) ^ srow) * 8;        // swizzled source granule
    const int sw   = c16 & 7;                        // fragment-read swizzle key

    f32x4 acc[4][4] = {};

    for (int kt = 0; kt < K / 64; ++kt) {
        const int kk = kt * 64;
        #pragma unroll
        for (int i = 0; i < 4; ++i) {
            const int arow = 32 * w + 8 * i;
            __builtin_amdgcn_global_load_lds(
                (const __attribute__((address_space(1))) void*)(A + (size_t)(m0 + arow + srow) * K + kk + scol),
                (__attribute__((address_space(3))) void*)(&As[arow * 64]),
                16, 0, 0);
            __builtin_amdgcn_global_load_lds(
                (const __attribute__((address_space(1))) void*)(Bt + (size_t)(n0 + arow + srow) * K + kk + scol),
                (__attribute__((address_space(3))) void*)(&Bs[arow * 64]),
                16, 0, 0);
        }
        __syncthreads();

        #pragma unroll
        for (int ks = 0; ks < 2; ++ks) {
            const int go = ((ks * 4 + quad) ^ sw) * 8;   // swizzled granule offset
            bf16x8 af[4], bfv[4];
            #pragma unroll
            for (int mb = 0; mb < 4; ++mb)
                af[mb] = *(const bf16x8*)&As[(wm * 64 + mb * 16 + c16) * 64 + go];
            #pragma unroll
            for (int nb = 0; nb < 4; ++nb)
                bfv[nb] = *(const bf16x8*)&Bs[(wn * 64 + nb * 16 + c16) * 64 + go];
            #pragma unroll
            for (int mb = 0; mb < 4; ++mb)
                #pragma unroll
                for (int nb = 0; nb < 4; ++nb)
                    acc[mb][nb] = MFMA16(af[mb], bfv[nb], acc[mb][nb]);
        }
        __syncthreads();
    }

    #pragma unroll
    for (int nb = 0; nb < 4; ++nb) {
        const int n = n0 + wn * 64 + nb * 16 + c16;
        const float bv = bias[n];
        const float sc = (n < oscale_n) ? oscale : 1.0f;
        #pragma unroll
        for (int mb = 0; mb < 4; ++mb) {
            const int mbase = m0 + wm * 64 + mb * 16 + quad * 4;
            #pragma unroll
            for (int r = 0; r < 4; ++r) {
                float v = (acc[mb][nb][r] + bv) * sc;
                if (OUT_BF16)
                    ((bf16*)outp)[(size_t)(mbase + r) * N + n] = (bf16)v;
                else
                    ((float*)outp)[(size_t)(mbase + r) * N + n] = v;
            }
        }
    }
}

// ---------------------------------------------------------------------------
// Flash-style causal attention, v10:
//  - PREFETCH ORDER FIX: V global loads issued BEFORE K global_load_lds.
//    vmcnt is FIFO: with V oldest, the auto-wait before vs_store is
//    vmcnt(2) (K-stage stays in flight through compute, retires under the
//    loop __syncthreads). Old order forced vmcnt(0) mid-iter = exposed HBM
//    stall every k-iter.
//  - lsum: 4 parallel accumulators (f32x4) instead of one 16-deep 4-cyc
//    dependent add chain per mb; horizontal add in epilogue.
//  - 3-way split-K, two-phase fold, S^T=K*Q^T register P, swizzled Vs kept.
// ---------------------------------------------------------------------------
__global__ __launch_bounds__(256, 2) void attn_fwd(const bf16* __restrict__ qkv,
                                                   bf16* __restrict__ yp0,
                                                   bf16* __restrict__ yp1,
                                                   bf16* __restrict__ yp2,
                                                   float* __restrict__ lp) {
    __shared__ __align__(16) bf16 Ks2[2][4096];       // [buf][512*key8 + 64*dgrp + 8*k7 + d7]
    __shared__ __align__(16) bf16 Vs[2][64 * 64];     // [buf] V^T [d][key], granule-XOR swizzled
#if !HAVE_K16
    __shared__ __align__(16) bf16 Ps[4][32 * 72];     // fallback: [wave][q][key]
#endif

    const int x    = blockIdx.x;                      // 0..23
    const int xq   = x / 3;                           // 0..7 : q-tile pair index
    const int sgl  = x - 3 * xq;                      // 0..2 : key segment
    const int h    = blockIdx.y;
    const int bb   = blockIdx.z;
    const int tid  = threadIdx.x;
    const int w    = tid >> 6;
    const int lane = tid & 63;
    const int quad = lane >> 4, c16 = lane & 15;

    const size_t base = (size_t)(bb * T) * QKV_LD;

    const int g = tid >> 5;   // 0..7  : d-group for V staging
    const int p = tid & 31;   // 0..31 : key-pair for V staging

    auto vs_store = [&](bf16* vbuf, const bf16x8& va, const bf16x8& vb) {
        #pragma unroll
        for (int j = 0; j < 8; ++j) {
            union { bf16 hh[2]; uint32_t u; } pk;
            pk.hh[0] = va[j]; pk.hh[1] = vb[j];
            const int row = 8 * g + j;
            *(uint32_t*)&vbuf[row * 64 + (((p >> 1) ^ (row & 15)) << 2) + ((p & 1) << 1)] = pk.u;
        }
    };

    bf16* __restrict__ ydst = (sgl == 0) ? yp0 : ((sgl == 1) ? yp1 : yp2);
    float* __restrict__ ldst = lp + (size_t)sgl * Mrows * Hn;

    for (int ph = 0; ph < 2; ++ph) {
        const int qt = ph ? xq : (15 - xq);           // phase 0: heavy tile
        const int q0 = qt * 128;
        const int rowbase = q0 + w * 32;

        const int n = 2 * qt + 2;
        int f0, f1;
        if (ph == 0) { f0 = (n + 2) / 3; f1 = (n + 1) / 3; }
        else         { f0 = n / 3;       f1 = (n + 1) / 3; }
        const int start = (sgl == 0) ? 0 : ((sgl == 1) ? f0 : f0 + f1);
        const int nkt   = (sgl == 0) ? f0 : ((sgl == 1) ? f1 : n - f0 - f1);

        __syncthreads();

        // ---- prologue: V loads first (vmcnt FIFO), then K stage ----
        {
            const int kb = start * 64;
            const bf16* vp = qkv + base + (size_t)(kb + 2 * p) * QKV_LD + 2 * Cd + h * 64 + g * 8;
            bf16x8 va = *(const bf16x8*)vp;
            bf16x8 vb = *(const bf16x8*)(vp + QKV_LD);
            #pragma unroll
            for (int ii = 0; ii < 2; ++ii) {
                const int i = 2 * w + ii;
                const bf16* gp = qkv + base + (size_t)(kb + 8 * i + (lane & 7)) * QKV_LD + Cd + h * 64 + (lane >> 3) * 8;
                __builtin_amdgcn_global_load_lds(
                    (const __attribute__((address_space(1))) void*)gp,
                    (__attribute__((address_space(3))) void*)(&Ks2[0][i * 512]), 16, 0, 0);
            }
            vs_store(Vs[0], va, vb);
        }

        bf16x8 qf[2][2];
        #pragma unroll
        for (int mb = 0; mb < 2; ++mb) {
            const bf16* qp = qkv + base + (size_t)(rowbase + 16 * mb + c16) * QKV_LD + h * 64 + quad * 8;
            qf[mb][0] = *(const bf16x8*)qp;
            qf[mb][1] = *(const bf16x8*)(qp + 32);
        }

        f32x4 yacc[2][4] = {};
        f32x4 lacc[2] = {};        // 4 parallel l-partials per mb

        for (int j = 0; j < nkt; ++j) {
            const int cur = j & 1, nxt = cur ^ 1;
            const int k0 = (start + j) * 64;
            __syncthreads();

            // prefetch tile start+j+1: V loads FIRST, K stage after
            bf16x8 va, vb;
            const bool more = (j + 1 < nkt);
            if (more) {
                const int kn = k0 + 64;
                const bf16* vp = qkv + base + (size_t)(kn + 2 * p) * QKV_LD + 2 * Cd + h * 64 + g * 8;
                va = *(const bf16x8*)vp;
                vb = *(const bf16x8*)(vp + QKV_LD);
                #pragma unroll
                for (int ii = 0; ii < 2; ++ii) {
                    const int i = 2 * w + ii;
                    const bf16* gp = qkv + base + (size_t)(kn + 8 * i + (lane & 7)) * QKV_LD + Cd + h * 64 + (lane >> 3) * 8;
                    __builtin_amdgcn_global_load_lds(
                        (const __attribute__((address_space(1))) void*)gp,
                        (__attribute__((address_space(3))) void*)(&Ks2[nxt][i * 512]), 16, 0, 0);
                }
            }

            if (k0 <= rowbase + 31) {   // wave-uniform skip of fully-masked tiles
                f32x4 s[2][4] = {};
                #pragma unroll
                for (int ks = 0; ks < 2; ++ks)
                    #pragma unroll
                    for (int blk = 0; blk < 4; ++blk) {
                        const bf16x8 kf = *(const bf16x8*)
                            &Ks2[cur][(2 * blk + (c16 >> 3)) * 512 + (4 * ks + quad) * 64 + (c16 & 7) * 8];
                        #pragma unroll
                        for (int mb = 0; mb < 2; ++mb)
                            s[mb][blk] = MFMA16(kf, qf[mb][ks], s[mb][blk]);
                    }

#if HAVE_K16
                union B4 { bf16x4 v; s16x4 s; } pb[2][4];
#endif
                #pragma unroll
                for (int mb = 0; mb < 2; ++mb) {
                    const int rb = rowbase + 16 * mb;
                    const int qglob = rb + c16;
                    const bool needMask = (k0 + 63 > rb);
                    #pragma unroll
                    for (int blk = 0; blk < 4; ++blk) {
                        #pragma unroll
                        for (int r = 0; r < 4; ++r) {
                            const int key = k0 + blk * 16 + quad * 4 + r;
                            float e = s[mb][blk][r];
                            if (needMask) e = (key > qglob) ? -INFINITY : e;
                            float pv = EXP2(e);
                            lacc[mb][r] += pv;
#if HAVE_K16
                            pb[mb][blk].v[r] = (bf16)pv;
#else
                            Ps[w][(mb * 16 + c16) * 72 + blk * 16 + quad * 4 + r] = (bf16)pv;
#endif
                        }
                    }
                }

#if HAVE_K16
                #pragma unroll
                for (int blk = 0; blk < 4; ++blk)
                    #pragma unroll
                    for (int d16 = 0; d16 < 4; ++d16) {
                        union B4u { bf16x4 v; s16x4 s; } vf;
                        vf.v = *(const bf16x4*)
                            &Vs[cur][(d16 * 16 + c16) * 64 + ((((blk << 2) | quad) ^ c16) << 2)];
                        #pragma unroll
                        for (int mb = 0; mb < 2; ++mb)
                            yacc[mb][d16] = __builtin_amdgcn_mfma_f32_16x16x16bf16_1k(
                                vf.s, pb[mb][blk].s, yacc[mb][d16], 0, 0, 0);
                    }
#else
                asm volatile("s_waitcnt lgkmcnt(0)" ::: "memory");
                #pragma unroll
                for (int ks = 0; ks < 2; ++ks) {
                    bf16x8 pf0 = *(const bf16x8*)&Ps[w][(0 * 16 + c16) * 72 + ks * 32 + quad * 8];
                    bf16x8 pf1 = *(const bf16x8*)&Ps[w][(1 * 16 + c16) * 72 + ks * 32 + quad * 8];
                    #pragma unroll
                    for (int d16 = 0; d16 < 4; ++d16) {
                        const int row = d16 * 16 + c16;
                        const int g0 = ks * 8 + quad * 2;
                        bf16x4 lo = *(const bf16x4*)&Vs[cur][row * 64 + ((g0 ^ c16) << 2)];
                        bf16x4 hi = *(const bf16x4*)&Vs[cur][row * 64 + (((g0 + 1) ^ c16) << 2)];
                        bf16x8 vfr;
                        vfr[0] = lo[0]; vfr[1] = lo[1]; vfr[2] = lo[2]; vfr[3] = lo[3];
                        vfr[4] = hi[0]; vfr[5] = hi[1]; vfr[6] = hi[2]; vfr[7] = hi[3];
                        yacc[0][d16] = MFMA16(pf0, vfr, yacc[0][d16]);
                        yacc[1][d16] = MFMA16(pf1, vfr, yacc[1][d16]);
                    }
                }
#endif
            }

            // write prefetched V (compiler wait here is now vmcnt(2), not 0)
            if (more)
                vs_store(Vs[nxt], va, vb);
        }

        // ---- l reduction: horizontal 4->1, then quad fold (lane bits 4,5) ----
        float lsum[2];
        #pragma unroll
        for (int mb = 0; mb < 2; ++mb) {
            lsum[mb] = (lacc[mb][0] + lacc[mb][1]) + (lacc[mb][2] + lacc[mb][3]);
            lsum[mb] += __shfl_xor(lsum[mb], 16);
            lsum[mb] += __shfl_xor(lsum[mb], 32);
        }

        // ---- epilogue: UNNORMALIZED partial + l (zeros if nkt == 0) ----
#if HAVE_K16
        #pragma unroll
        for (int mb = 0; mb < 2; ++mb) {
            const int row = rowbase + 16 * mb + c16;
            bf16* yw = ydst + (size_t)(bb * T + row) * Cd + h * 64;
            #pragma unroll
            for (int d16 = 0; d16 < 4; ++d16) {
                bf16x4 o;
                #pragma unroll
                for (int r = 0; r < 4; ++r)
                    o[r] = (bf16)(yacc[mb][d16][r]);
                *(bf16x4*)(yw + d16 * 16 + quad * 4) = o;
            }
            if (quad == 0)
                ldst[(size_t)(bb * T + row) * Hn + h] = lsum[mb];
        }
#else
        #pragma unroll
        for (int mb = 0; mb < 2; ++mb)
            #pragma unroll
            for (int r = 0; r < 4; ++r) {
                const float lsv = __shfl(lsum[mb], quad * 4 + r);
                const int row = rowbase + 16 * mb + quad * 4 + r;
                bf16* yw = ydst + (size_t)(bb * T + row) * Cd + h * 64;
                #pragma unroll
                for (int d16 = 0; d16 < 4; ++d16)
                    yw[d16 * 16 + c16] = (bf16)(yacc[mb][d16][r]);
                if (c16 == 0)
                    ldst[(size_t)(bb * T + row) * Hn + h] = lsv;
            }
#endif
    }
}

// ---------------------------------------------------------------------------
// Combine split-K partials: y = (y0 + y1 + y2) / (l0 + l1 + l2).
// ---------------------------------------------------------------------------
__global__ __launch_bounds__(256) void attn_combine(const bf16* __restrict__ yp0,
                                                    const bf16* __restrict__ yp1,
                                                    const bf16* __restrict__ yp2,
                                                    const float* __restrict__ lp,
                                                    bf16* __restrict__ y) {
    int i = (blockIdx.x * 256 + threadIdx.x) * 8;
    int row = i >> 10;          // / Cd
    int hh  = (i & 1023) >> 6;  // head
    const size_t S = (size_t)Mrows * Hn;
    const size_t li = (size_t)row * Hn + hh;
    float l = lp[li] + lp[S + li] + lp[2 * S + li];
    float inv = 1.f / l;
    bf16x8 a = *(const bf16x8*)(yp0 + i);
    bf16x8 b = *(const bf16x8*)(yp1 + i);
    bf16x8 c = *(const bf16x8*)(yp2 + i);
    bf16x8 o;
    #pragma unroll
    for (int j = 0; j < 8; ++j)
        o[j] = (bf16)(((float)a[j] + (float)b[j] + (float)c[j]) * inv);
    *(bf16x8*)(y + i) = o;
}

// ---------------------------------------------------------------------------
extern "C" void kernel_launch(void* const* d_in, const int* in_sizes, int n_in,
                              void* d_out, int out_size, void* d_ws, size_t ws_size,
                              hipStream_t stream) {
    const float* x      = (const float*)d_in[0];
    const float* W_attn = (const float*)d_in[1];
    const float* b_attn = (const float*)d_in[2];
    const float* W_proj = (const float*)d_in[3];
    const float* b_proj = (const float*)d_in[4];
    float* out = (float*)d_out;

    bf16* xb   = (bf16*)d_ws;                               // 16.8 MB (yp2 after gemm1)
    bf16* Wat  = xb  + (size_t)Mrows * Cd;                  // 6.3 MB  (lp after gemm1)
    bf16* Wpt  = Wat + (size_t)QKV_LD * Cd;                 // 2.1 MB
    bf16* qkv  = Wpt + (size_t)Cd * Cd;                     // 50.3 MB
    bf16* yb   = qkv + (size_t)Mrows * QKV_LD;              // 16.8 MB (yp0 + combined)
    bf16* yp1  = yb  + (size_t)Mrows * Cd;                  // 16.8 MB
    bf16*  yp2 = xb;                                        // 3rd split-K partial
    float* lp  = (float*)Wat;                               // 3 x Mrows x Hn = 1.57 MB

    prep<<<8192, 256, 0, stream>>>(x, W_attn, W_proj, xb, Wat, Wpt);

    // Q columns (n < 1024) pre-scaled by 1/sqrt(D)*log2e for the attn exp2
    gemm256<QKV_LD, true><<<dim3((Mrows / 256) * (QKV_LD / 256)), dim3(512), 0, stream>>>(
        xb, Wat, b_attn, qkv, QSCALE, Cd);

    attn_fwd<<<dim3(24, Hn, Bsz), 256, 0, stream>>>(qkv, yb, yp1, yp2, lp);
    attn_combine<<<(Mrows * Cd) / (256 * 8), 256, 0, stream>>>(yb, yp1, yp2, lp, yb);

    gemm_bf16<Cd, false><<<dim3(Cd / 128, Mrows / 128), 256, 0, stream>>>(
        yb, Wpt, b_proj, out, 1.0f, 0);
}

// Round 6
// 270.581 us; speedup vs baseline: 1.0391x; 1.0391x over previous
//
#include <hip/hip_runtime.h>
#include <cstdint>
#include <cstddef>

typedef __bf16 bf16;
typedef __bf16 bf16x8 __attribute__((ext_vector_type(8)));
typedef __bf16 bf16x4 __attribute__((ext_vector_type(4)));
typedef short  s16x4  __attribute__((ext_vector_type(4)));
typedef float  f32x4  __attribute__((ext_vector_type(4)));

#define MFMA16(a, b, c) __builtin_amdgcn_mfma_f32_16x16x32_bf16((a), (b), (c), 0, 0, 0)

#if __has_builtin(__builtin_amdgcn_mfma_f32_16x16x16bf16_1k)
#define HAVE_K16 1
#else
#define HAVE_K16 0
#endif

#if __has_builtin(__builtin_amdgcn_exp2f)
#define EXP2(x) __builtin_amdgcn_exp2f(x)
#else
#define EXP2(x) exp2f(x)
#endif

// Problem constants
constexpr int Bsz = 4;
constexpr int T   = 2048;
constexpr int Cd  = 1024;
constexpr int Hn  = 16;
constexpr int Mrows = Bsz * T;          // 8192
constexpr int QKV_LD = 3 * Cd;          // 3072

// softmax scale folded into Q at GEMM1 epilogue: 1/sqrt(64) * log2(e)
constexpr float QSCALE = 0.125f * 1.4426950408889634f;

// ---------------------------------------------------------------------------
// Fused prep: x fp32->bf16 cvt  +  W_attn transpose  +  W_proj transpose.
// One launch instead of three (round-5: ~8 us saved, kept).
// Block ranges: [0,4096) cvt, [4096,7168) W_attn, [7168,8192) W_proj.
// ---------------------------------------------------------------------------
__global__ __launch_bounds__(256) void prep(const float* __restrict__ x,
                                            const float* __restrict__ W_attn,
                                            const float* __restrict__ W_proj,
                                            bf16* __restrict__ xb,
                                            bf16* __restrict__ Wat,
                                            bf16* __restrict__ Wpt) {
    __shared__ float tile[32][33];
    const int bid = blockIdx.x;
    const int tid = threadIdx.x;
    if (bid < 4096) {                       // ---- cvt x -> xb (8 elems/thread)
        const int i = (bid * 256 + tid) * 8;
        float4 a = *(const float4*)(x + i);
        float4 b = *(const float4*)(x + i + 4);
        bf16x8 o;
        o[0] = (bf16)a.x; o[1] = (bf16)a.y; o[2] = (bf16)a.z; o[3] = (bf16)a.w;
        o[4] = (bf16)b.x; o[5] = (bf16)b.y; o[6] = (bf16)b.z; o[7] = (bf16)b.w;
        *(bf16x8*)(xb + i) = o;
        return;
    }
    const float* W; bf16* Wt; int NDIM, bx, by;
    if (bid < 4096 + 3072) {
        const int r = bid - 4096;
        W = W_attn; Wt = Wat; NDIM = QKV_LD; bx = r % 96; by = r / 96;
    } else {
        const int r = bid - 7168;
        W = W_proj; Wt = Wpt; NDIM = Cd; bx = r & 31; by = r >> 5;
    }
    const int k0 = by * 32, n0 = bx * 32;
    const int tx = tid & 31, ty = tid >> 5;
    #pragma unroll
    for (int r = 0; r < 32; r += 8)
        tile[r + ty][tx] = W[(size_t)(k0 + r + ty) * NDIM + n0 + tx];
    __syncthreads();
    #pragma unroll
    for (int r = 0; r < 32; r += 8)
        Wt[(size_t)(n0 + r + ty) * Cd + k0 + tx] = (bf16)tile[tx][r + ty];
}

// ---------------------------------------------------------------------------
// 256x256-tile 8-wave bf16 GEMM, v2 deep-pipelined schedule (round-4, kept).
// 24 ds_read_b128/K-tile, 4 barriers/K-tile, counted vmcnt (never 0 in loop),
// granule-XOR swizzle, XCD-aware remap. FIFO audit in round-4 notes.
// ---------------------------------------------------------------------------
template <int N, bool OUT_BF16>
__global__ __launch_bounds__(512, 2) void gemm256(const bf16* __restrict__ A,
                                                  const bf16* __restrict__ Bt,
                                                  const float* __restrict__ bias,
                                                  void* __restrict__ outp,
                                                  float oscale, int oscale_n) {
    constexpr int K  = 1024;
    constexpr int KT = K / 64;          // 16 K-tiles
    __shared__ __align__(16) bf16 lds[65536];   // A: [0,32768), B: [32768,65536)

    const int tid  = threadIdx.x;
    const int wv   = tid >> 6;          // 0..7
    const int lane = tid & 63;
    const int wm   = wv >> 2;           // 0..1 : M-wave
    const int wn   = wv & 3;            // 0..3 : N-wave
    const int quad = lane >> 4, c16 = lane & 15;
    const int sw   = c16 & 7;

    const int lin = (int)blockIdx.x;
    const int x8  = lin & 7;
    const int q   = lin >> 3;
    const int m0  = (x8 + 8 * (q & 3)) * 256;
    const int n0  = (q >> 2) * 256;

    auto stage = [&](int kt, int isB, int h) {
        if (kt >= KT) return;
        const int db = kt & 1;
        #pragma unroll
        for (int r = 0; r < 2; ++r) {
            const int idx  = r * 512 + tid;
            const int slot = idx >> 3;
            const int gq   = idx & 7;
            const int kg   = kt * 64 + ((gq ^ (slot & 7)) << 3);
            const bf16* src;
            if (isB) {
                const int col = ((slot >> 5) << 6) + h * 32 + (slot & 31);
                src = Bt + (size_t)(n0 + col) * K + kg;
            } else {
                const int row = ((slot >> 6) << 7) + h * 64 + (slot & 63);
                src = A + (size_t)(m0 + row) * K + kg;
            }
            bf16* dst = &lds[(isB ? 32768 : 0) + db * 16384 + h * 8192 + (r * 8 + wv) * 512];
            __builtin_amdgcn_global_load_lds(
                (const __attribute__((address_space(1))) void*)src,
                (__attribute__((address_space(3))) void*)dst, 16, 0, 0);
        }
    };

    f32x4 acc[8][4] = {};
    bf16x8 af[4][2], b0[2][2], b1[2][2];

#define READ_A(QM, DB)                                                           \
    _Pragma("unroll") for (int mq = 0; mq < 4; ++mq)                             \
        _Pragma("unroll") for (int ks = 0; ks < 2; ++ks)                         \
            af[mq][ks] = *(const bf16x8*)&lds[(DB) * 16384 + (QM) * 8192 +       \
                (wm * 64 + mq * 16 + c16) * 64 + (((ks * 4 + quad) ^ sw) << 3)];
#define READ_B(DST, QN, DB)                                                      \
    _Pragma("unroll") for (int nq = 0; nq < 2; ++nq)                             \
        _Pragma("unroll") for (int ks = 0; ks < 2; ++ks)                         \
            DST[nq][ks] = *(const bf16x8*)&lds[32768 + (DB) * 16384 + (QN) * 8192 + \
                (wn * 32 + nq * 16 + c16) * 64 + (((ks * 4 + quad) ^ sw) << 3)];
#define MFMA_Q(QM, QN, BREG)                                                     \
    __builtin_amdgcn_s_setprio(1);                                               \
    _Pragma("unroll") for (int mq = 0; mq < 4; ++mq)                             \
        _Pragma("unroll") for (int nq = 0; nq < 2; ++nq)                         \
            _Pragma("unroll") for (int ks = 0; ks < 2; ++ks)                     \
                acc[(QM) * 4 + mq][(QN) * 2 + nq] =                              \
                    MFMA16(af[mq][ks], BREG[nq][ks],                             \
                           acc[(QM) * 4 + mq][(QN) * 2 + nq]);                   \
    __builtin_amdgcn_s_setprio(0);
#define VMBAR(NSTR)                                                              \
    asm volatile("s_waitcnt vmcnt(" NSTR ")" ::: "memory");                      \
    __builtin_amdgcn_s_barrier();

    stage(0, 0, 0); stage(0, 1, 0); stage(0, 1, 1); stage(0, 0, 1);
    VMBAR("4")

    #pragma unroll 1
    for (int u = 0; u < KT - 1; ++u) {
        const int db = u & 1;
        const int kn = u + 1;
        READ_A(0, db)
        READ_B(b0, 0, db)
        stage(kn, 0, 0); stage(kn, 1, 0);
        MFMA_Q(0, 0, b0)
        VMBAR("6")
        READ_B(b1, 1, db)
        stage(kn, 1, 1);
        MFMA_Q(0, 1, b1)
        VMBAR("6")
        READ_A(1, db)
        stage(kn, 0, 1);
        MFMA_Q(1, 0, b0)
        __builtin_amdgcn_s_barrier();
        MFMA_Q(1, 1, b1)
        VMBAR("4")
    }

    READ_A(0, 1)
    READ_B(b0, 0, 1)
    MFMA_Q(0, 0, b0)
    VMBAR("2")
    READ_B(b1, 1, 1)
    MFMA_Q(0, 1, b1)
    VMBAR("0")
    READ_A(1, 1)
    MFMA_Q(1, 0, b0)
    MFMA_Q(1, 1, b1)

#undef READ_A
#undef READ_B
#undef MFMA_Q
#undef VMBAR

    #pragma unroll
    for (int nb = 0; nb < 4; ++nb) {
        const int n = n0 + wn * 64 + nb * 16 + c16;
        const float bv = bias[n];
        const float sc = (n < oscale_n) ? oscale : 1.0f;
        #pragma unroll
        for (int mb = 0; mb < 8; ++mb) {
            const int mbase = m0 + wm * 128 + mb * 16 + quad * 4;
            #pragma unroll
            for (int r = 0; r < 4; ++r) {
                float val = (acc[mb][nb][r] + bv) * sc;
                if (OUT_BF16)
                    ((bf16*)outp)[(size_t)(mbase + r) * N + n] = (bf16)val;
                else
                    ((float*)outp)[(size_t)(mbase + r) * N + n] = val;
            }
        }
    }
}

// ---------------------------------------------------------------------------
// bf16 MFMA GEMM, 128^2 (m97 pattern) — GEMM2 (N=1024). Granule-XOR swizzle
// + XCD remap.
// ---------------------------------------------------------------------------
template <int N, bool OUT_BF16>
__global__ __launch_bounds__(256) void gemm_bf16(const bf16* __restrict__ A,
                                                 const bf16* __restrict__ Bt,
                                                 const float* __restrict__ bias,
                                                 void* __restrict__ outp,
                                                 float oscale, int oscale_n) {
    constexpr int K = 1024;
    __shared__ __align__(16) bf16 As[128 * 64];
    __shared__ __align__(16) bf16 Bs[128 * 64];

    const int tid  = threadIdx.x;
    const int w    = tid >> 6;
    const int lane = tid & 63;
    const int wm   = w & 1, wn = w >> 1;
    const int quad = lane >> 4, c16 = lane & 15;

    const int lin = (int)(blockIdx.y * gridDim.x + blockIdx.x);
    const int x8  = lin & 7;
    const int q   = lin >> 3;
    const int m0  = (x8 + 8 * (q & 7)) * 128;
    const int n0  = (q >> 3) * 128;

    const int srow = lane >> 3;                      // 0..7
    const int scol = ((lane & 7) ^ srow) * 8;        // swizzled source granule
    const int sw   = c16 & 7;                        // fragment-read swizzle key

    f32x4 acc[4][4] = {};

    for (int kt = 0; kt < K / 64; ++kt) {
        const int kk = kt * 64;
        #pragma unroll
        for (int i = 0; i < 4; ++i) {
            const int arow = 32 * w + 8 * i;
            __builtin_amdgcn_global_load_lds(
                (const __attribute__((address_space(1))) void*)(A + (size_t)(m0 + arow + srow) * K + kk + scol),
                (__attribute__((address_space(3))) void*)(&As[arow * 64]),
                16, 0, 0);
            __builtin_amdgcn_global_load_lds(
                (const __attribute__((address_space(1))) void*)(Bt + (size_t)(n0 + arow + srow) * K + kk + scol),
                (__attribute__((address_space(3))) void*)(&Bs[arow * 64]),
                16, 0, 0);
        }
        __syncthreads();

        #pragma unroll
        for (int ks = 0; ks < 2; ++ks) {
            const int go = ((ks * 4 + quad) ^ sw) * 8;   // swizzled granule offset
            bf16x8 af[4], bfv[4];
            #pragma unroll
            for (int mb = 0; mb < 4; ++mb)
                af[mb] = *(const bf16x8*)&As[(wm * 64 + mb * 16 + c16) * 64 + go];
            #pragma unroll
            for (int nb = 0; nb < 4; ++nb)
                bfv[nb] = *(const bf16x8*)&Bs[(wn * 64 + nb * 16 + c16) * 64 + go];
            #pragma unroll
            for (int mb = 0; mb < 4; ++mb)
                #pragma unroll
                for (int nb = 0; nb < 4; ++nb)
                    acc[mb][nb] = MFMA16(af[mb], bfv[nb], acc[mb][nb]);
        }
        __syncthreads();
    }

    #pragma unroll
    for (int nb = 0; nb < 4; ++nb) {
        const int n = n0 + wn * 64 + nb * 16 + c16;
        const float bv = bias[n];
        const float sc = (n < oscale_n) ? oscale : 1.0f;
        #pragma unroll
        for (int mb = 0; mb < 4; ++mb) {
            const int mbase = m0 + wm * 64 + mb * 16 + quad * 4;
            #pragma unroll
            for (int r = 0; r < 4; ++r) {
                float v = (acc[mb][nb][r] + bv) * sc;
                if (OUT_BF16)
                    ((bf16*)outp)[(size_t)(mbase + r) * N + n] = (bf16)v;
                else
                    ((float*)outp)[(size_t)(mbase + r) * N + n] = v;
            }
        }
    }
}

// ---------------------------------------------------------------------------
// Flash-style causal attention — EXACT round-4 version (measured 88.0 us;
// round-5's reorder+lacc bundle regressed to 105 and is fully reverted).
// 3-way split-K, two-phase fold, S^T=K*Q^T register P, swizzled Vs.
// ---------------------------------------------------------------------------
__global__ __launch_bounds__(256, 2) void attn_fwd(const bf16* __restrict__ qkv,
                                                   bf16* __restrict__ yp0,
                                                   bf16* __restrict__ yp1,
                                                   bf16* __restrict__ yp2,
                                                   float* __restrict__ lp) {
    __shared__ __align__(16) bf16 Ks2[2][4096];       // [buf][512*key8 + 64*dgrp + 8*k7 + d7]
    __shared__ __align__(16) bf16 Vs[2][64 * 64];     // [buf] V^T [d][key], granule-XOR swizzled
#if !HAVE_K16
    __shared__ __align__(16) bf16 Ps[4][32 * 72];     // fallback: [wave][q][key]
#endif

    const int x    = blockIdx.x;                      // 0..23
    const int xq   = x / 3;                           // 0..7 : q-tile pair index
    const int sgl  = x - 3 * xq;                      // 0..2 : key segment
    const int h    = blockIdx.y;
    const int bb   = blockIdx.z;
    const int tid  = threadIdx.x;
    const int w    = tid >> 6;
    const int lane = tid & 63;
    const int quad = lane >> 4, c16 = lane & 15;

    const size_t base = (size_t)(bb * T) * QKV_LD;

    const int g = tid >> 5;   // 0..7  : d-group for V staging
    const int p = tid & 31;   // 0..31 : key-pair for V staging

    auto vs_store = [&](bf16* vbuf, const bf16x8& va, const bf16x8& vb) {
        #pragma unroll
        for (int j = 0; j < 8; ++j) {
            union { bf16 hh[2]; uint32_t u; } pk;
            pk.hh[0] = va[j]; pk.hh[1] = vb[j];
            const int row = 8 * g + j;
            *(uint32_t*)&vbuf[row * 64 + (((p >> 1) ^ (row & 15)) << 2) + ((p & 1) << 1)] = pk.u;
        }
    };

    bf16* __restrict__ ydst = (sgl == 0) ? yp0 : ((sgl == 1) ? yp1 : yp2);
    float* __restrict__ ldst = lp + (size_t)sgl * Mrows * Hn;

    for (int ph = 0; ph < 2; ++ph) {
        const int qt = ph ? xq : (15 - xq);           // phase 0: heavy tile
        const int q0 = qt * 128;
        const int rowbase = q0 + w * 32;

        const int n = 2 * qt + 2;
        int f0, f1;
        if (ph == 0) { f0 = (n + 2) / 3; f1 = (n + 1) / 3; }
        else         { f0 = n / 3;       f1 = (n + 1) / 3; }
        const int start = (sgl == 0) ? 0 : ((sgl == 1) ? f0 : f0 + f1);
        const int nkt   = (sgl == 0) ? f0 : ((sgl == 1) ? f1 : n - f0 - f1);

        __syncthreads();

        {
            const int kb = start * 64;
            #pragma unroll
            for (int ii = 0; ii < 2; ++ii) {
                const int i = 2 * w + ii;
                const bf16* gp = qkv + base + (size_t)(kb + 8 * i + (lane & 7)) * QKV_LD + Cd + h * 64 + (lane >> 3) * 8;
                __builtin_amdgcn_global_load_lds(
                    (const __attribute__((address_space(1))) void*)gp,
                    (__attribute__((address_space(3))) void*)(&Ks2[0][i * 512]), 16, 0, 0);
            }
            const bf16* vp = qkv + base + (size_t)(kb + 2 * p) * QKV_LD + 2 * Cd + h * 64 + g * 8;
            bf16x8 va = *(const bf16x8*)vp;
            bf16x8 vb = *(const bf16x8*)(vp + QKV_LD);
            vs_store(Vs[0], va, vb);
        }

        bf16x8 qf[2][2];
        #pragma unroll
        for (int mb = 0; mb < 2; ++mb) {
            const bf16* qp = qkv + base + (size_t)(rowbase + 16 * mb + c16) * QKV_LD + h * 64 + quad * 8;
            qf[mb][0] = *(const bf16x8*)qp;
            qf[mb][1] = *(const bf16x8*)(qp + 32);
        }

        f32x4 yacc[2][4] = {};
        float lsum[2] = {};

        for (int j = 0; j < nkt; ++j) {
            const int cur = j & 1, nxt = cur ^ 1;
            const int k0 = (start + j) * 64;
            __syncthreads();

            bf16x8 va, vb;
            const bool more = (j + 1 < nkt);
            if (more) {
                const int kn = k0 + 64;
                #pragma unroll
                for (int ii = 0; ii < 2; ++ii) {
                    const int i = 2 * w + ii;
                    const bf16* gp = qkv + base + (size_t)(kn + 8 * i + (lane & 7)) * QKV_LD + Cd + h * 64 + (lane >> 3) * 8;
                    __builtin_amdgcn_global_load_lds(
                        (const __attribute__((address_space(1))) void*)gp,
                        (__attribute__((address_space(3))) void*)(&Ks2[nxt][i * 512]), 16, 0, 0);
                }
                const bf16* vp = qkv + base + (size_t)(kn + 2 * p) * QKV_LD + 2 * Cd + h * 64 + g * 8;
                va = *(const bf16x8*)vp;
                vb = *(const bf16x8*)(vp + QKV_LD);
            }

            if (k0 <= rowbase + 31) {
                f32x4 s[2][4] = {};
                #pragma unroll
                for (int ks = 0; ks < 2; ++ks)
                    #pragma unroll
                    for (int blk = 0; blk < 4; ++blk) {
                        const bf16x8 kf = *(const bf16x8*)
                            &Ks2[cur][(2 * blk + (c16 >> 3)) * 512 + (4 * ks + quad) * 64 + (c16 & 7) * 8];
                        #pragma unroll
                        for (int mb = 0; mb < 2; ++mb)
                            s[mb][blk] = MFMA16(kf, qf[mb][ks], s[mb][blk]);
                    }

#if HAVE_K16
                union B4 { bf16x4 v; s16x4 s; } pb[2][4];
#endif
                #pragma unroll
                for (int mb = 0; mb < 2; ++mb) {
                    const int rb = rowbase + 16 * mb;
                    const int qglob = rb + c16;
                    const bool needMask = (k0 + 63 > rb);
                    #pragma unroll
                    for (int blk = 0; blk < 4; ++blk) {
                        #pragma unroll
                        for (int r = 0; r < 4; ++r) {
                            const int key = k0 + blk * 16 + quad * 4 + r;
                            float e = s[mb][blk][r];
                            if (needMask) e = (key > qglob) ? -INFINITY : e;
                            float pv = EXP2(e);
                            lsum[mb] += pv;
#if HAVE_K16
                            pb[mb][blk].v[r] = (bf16)pv;
#else
                            Ps[w][(mb * 16 + c16) * 72 + blk * 16 + quad * 4 + r] = (bf16)pv;
#endif
                        }
                    }
                }

#if HAVE_K16
                #pragma unroll
                for (int blk = 0; blk < 4; ++blk)
                    #pragma unroll
                    for (int d16 = 0; d16 < 4; ++d16) {
                        union B4u { bf16x4 v; s16x4 s; } vf;
                        vf.v = *(const bf16x4*)
                            &Vs[cur][(d16 * 16 + c16) * 64 + ((((blk << 2) | quad) ^ c16) << 2)];
                        #pragma unroll
                        for (int mb = 0; mb < 2; ++mb)
                            yacc[mb][d16] = __builtin_amdgcn_mfma_f32_16x16x16bf16_1k(
                                vf.s, pb[mb][blk].s, yacc[mb][d16], 0, 0, 0);
                    }
#else
                asm volatile("s_waitcnt lgkmcnt(0)" ::: "memory");
                #pragma unroll
                for (int ks = 0; ks < 2; ++ks) {
                    bf16x8 pf0 = *(const bf16x8*)&Ps[w][(0 * 16 + c16) * 72 + ks * 32 + quad * 8];
                    bf16x8 pf1 = *(const bf16x8*)&Ps[w][(1 * 16 + c16) * 72 + ks * 32 + quad * 8];
                    #pragma unroll
                    for (int d16 = 0; d16 < 4; ++d16) {
                        const int row = d16 * 16 + c16;
                        const int g0 = ks * 8 + quad * 2;
                        bf16x4 lo = *(const bf16x4*)&Vs[cur][row * 64 + ((g0 ^ c16) << 2)];
                        bf16x4 hi = *(const bf16x4*)&Vs[cur][row * 64 + (((g0 + 1) ^ c16) << 2)];
                        bf16x8 vfr;
                        vfr[0] = lo[0]; vfr[1] = lo[1]; vfr[2] = lo[2]; vfr[3] = lo[3];
                        vfr[4] = hi[0]; vfr[5] = hi[1]; vfr[6] = hi[2]; vfr[7] = hi[3];
                        yacc[0][d16] = MFMA16(pf0, vfr, yacc[0][d16]);
                        yacc[1][d16] = MFMA16(pf1, vfr, yacc[1][d16]);
                    }
                }
#endif
            }

            if (more)
                vs_store(Vs[nxt], va, vb);
        }

        #pragma unroll
        for (int mb = 0; mb < 2; ++mb) {
            lsum[mb] += __shfl_xor(lsum[mb], 16);
            lsum[mb] += __shfl_xor(lsum[mb], 32);
        }

#if HAVE_K16
        #pragma unroll
        for (int mb = 0; mb < 2; ++mb) {
            const int row = rowbase + 16 * mb + c16;
            bf16* yw = ydst + (size_t)(bb * T + row) * Cd + h * 64;
            #pragma unroll
            for (int d16 = 0; d16 < 4; ++d16) {
                bf16x4 o;
                #pragma unroll
                for (int r = 0; r < 4; ++r)
                    o[r] = (bf16)(yacc[mb][d16][r]);
                *(bf16x4*)(yw + d16 * 16 + quad * 4) = o;
            }
            if (quad == 0)
                ldst[(size_t)(bb * T + row) * Hn + h] = lsum[mb];
        }
#else
        #pragma unroll
        for (int mb = 0; mb < 2; ++mb)
            #pragma unroll
            for (int r = 0; r < 4; ++r) {
                const float lsv = __shfl(lsum[mb], quad * 4 + r);
                const int row = rowbase + 16 * mb + quad * 4 + r;
                bf16* yw = ydst + (size_t)(bb * T + row) * Cd + h * 64;
                #pragma unroll
                for (int d16 = 0; d16 < 4; ++d16)
                    yw[d16 * 16 + c16] = (bf16)(yacc[mb][d16][r]);
                if (c16 == 0)
                    ldst[(size_t)(bb * T + row) * Hn + h] = lsv;
            }
#endif
    }
}

// ---------------------------------------------------------------------------
// Combine split-K partials: y = (y0 + y1 + y2) / (l0 + l1 + l2).
// ---------------------------------------------------------------------------
__global__ __launch_bounds__(256) void attn_combine(const bf16* __restrict__ yp0,
                                                    const bf16* __restrict__ yp1,
                                                    const bf16* __restrict__ yp2,
                                                    const float* __restrict__ lp,
                                                    bf16* __restrict__ y) {
    int i = (blockIdx.x * 256 + threadIdx.x) * 8;
    int row = i >> 10;          // / Cd
    int hh  = (i & 1023) >> 6;  // head
    const size_t S = (size_t)Mrows * Hn;
    const size_t li = (size_t)row * Hn + hh;
    float l = lp[li] + lp[S + li] + lp[2 * S + li];
    float inv = 1.f / l;
    bf16x8 a = *(const bf16x8*)(yp0 + i);
    bf16x8 b = *(const bf16x8*)(yp1 + i);
    bf16x8 c = *(const bf16x8*)(yp2 + i);
    bf16x8 o;
    #pragma unroll
    for (int j = 0; j < 8; ++j)
        o[j] = (bf16)(((float)a[j] + (float)b[j] + (float)c[j]) * inv);
    *(bf16x8*)(y + i) = o;
}

// ---------------------------------------------------------------------------
extern "C" void kernel_launch(void* const* d_in, const int* in_sizes, int n_in,
                              void* d_out, int out_size, void* d_ws, size_t ws_size,
                              hipStream_t stream) {
    const float* x      = (const float*)d_in[0];
    const float* W_attn = (const float*)d_in[1];
    const float* b_attn = (const float*)d_in[2];
    const float* W_proj = (const float*)d_in[3];
    const float* b_proj = (const float*)d_in[4];
    float* out = (float*)d_out;

    bf16* xb   = (bf16*)d_ws;                               // 16.8 MB (yp2 after gemm1)
    bf16* Wat  = xb  + (size_t)Mrows * Cd;                  // 6.3 MB  (lp after gemm1)
    bf16* Wpt  = Wat + (size_t)QKV_LD * Cd;                 // 2.1 MB
    bf16* qkv  = Wpt + (size_t)Cd * Cd;                     // 50.3 MB
    bf16* yb   = qkv + (size_t)Mrows * QKV_LD;              // 16.8 MB (yp0 + combined)
    bf16* yp1  = yb  + (size_t)Mrows * Cd;                  // 16.8 MB
    bf16*  yp2 = xb;                                        // 3rd split-K partial
    float* lp  = (float*)Wat;                               // 3 x Mrows x Hn = 1.57 MB

    prep<<<8192, 256, 0, stream>>>(x, W_attn, W_proj, xb, Wat, Wpt);

    // Q columns (n < 1024) pre-scaled by 1/sqrt(D)*log2e for the attn exp2
    gemm256<QKV_LD, true><<<dim3((Mrows / 256) * (QKV_LD / 256)), dim3(512), 0, stream>>>(
        xb, Wat, b_attn, qkv, QSCALE, Cd);

    attn_fwd<<<dim3(24, Hn, Bsz), 256, 0, stream>>>(qkv, yb, yp1, yp2, lp);
    attn_combine<<<(Mrows * Cd) / (256 * 8), 256, 0, stream>>>(yb, yp1, yp2, lp, yb);

    gemm_bf16<Cd, false><<<dim3(Cd / 128, Mrows / 128), 256, 0, stream>>>(
        yb, Wpt, b_proj, out, 1.0f, 0);
}

// Round 7
// 266.174 us; speedup vs baseline: 1.0563x; 1.0166x over previous
//
#include <hip/hip_runtime.h>
#include <cstdint>
#include <cstddef>

typedef __bf16 bf16;
typedef __bf16 bf16x8 __attribute__((ext_vector_type(8)));
typedef __bf16 bf16x4 __attribute__((ext_vector_type(4)));
typedef short  s16x4  __attribute__((ext_vector_type(4)));
typedef float  f32x4  __attribute__((ext_vector_type(4)));

#define MFMA16(a, b, c) __builtin_amdgcn_mfma_f32_16x16x32_bf16((a), (b), (c), 0, 0, 0)

#if __has_builtin(__builtin_amdgcn_mfma_f32_16x16x16bf16_1k)
#define HAVE_K16 1
#else
#define HAVE_K16 0
#endif

#if __has_builtin(__builtin_amdgcn_exp2f)
#define EXP2(x) __builtin_amdgcn_exp2f(x)
#else
#define EXP2(x) exp2f(x)
#endif

// Problem constants
constexpr int Bsz = 4;
constexpr int T   = 2048;
constexpr int Cd  = 1024;
constexpr int Hn  = 16;
constexpr int Mrows = Bsz * T;          // 8192
constexpr int QKV_LD = 3 * Cd;          // 3072

// softmax scale folded into Q at GEMM1 epilogue: 1/sqrt(64) * log2(e)
constexpr float QSCALE = 0.125f * 1.4426950408889634f;

// ---------------------------------------------------------------------------
// Fused prep: x fp32->bf16 cvt  +  W_attn transpose  +  W_proj transpose.
// ---------------------------------------------------------------------------
__global__ __launch_bounds__(256) void prep(const float* __restrict__ x,
                                            const float* __restrict__ W_attn,
                                            const float* __restrict__ W_proj,
                                            bf16* __restrict__ xb,
                                            bf16* __restrict__ Wat,
                                            bf16* __restrict__ Wpt) {
    __shared__ float tile[32][33];
    const int bid = blockIdx.x;
    const int tid = threadIdx.x;
    if (bid < 4096) {                       // ---- cvt x -> xb (8 elems/thread)
        const int i = (bid * 256 + tid) * 8;
        float4 a = *(const float4*)(x + i);
        float4 b = *(const float4*)(x + i + 4);
        bf16x8 o;
        o[0] = (bf16)a.x; o[1] = (bf16)a.y; o[2] = (bf16)a.z; o[3] = (bf16)a.w;
        o[4] = (bf16)b.x; o[5] = (bf16)b.y; o[6] = (bf16)b.z; o[7] = (bf16)b.w;
        *(bf16x8*)(xb + i) = o;
        return;
    }
    const float* W; bf16* Wt; int NDIM, bx, by;
    if (bid < 4096 + 3072) {
        const int r = bid - 4096;
        W = W_attn; Wt = Wat; NDIM = QKV_LD; bx = r % 96; by = r / 96;
    } else {
        const int r = bid - 7168;
        W = W_proj; Wt = Wpt; NDIM = Cd; bx = r & 31; by = r >> 5;
    }
    const int k0 = by * 32, n0 = bx * 32;
    const int tx = tid & 31, ty = tid >> 5;
    #pragma unroll
    for (int r = 0; r < 32; r += 8)
        tile[r + ty][tx] = W[(size_t)(k0 + r + ty) * NDIM + n0 + tx];
    __syncthreads();
    #pragma unroll
    for (int r = 0; r < 32; r += 8)
        Wt[(size_t)(n0 + r + ty) * Cd + k0 + tx] = (bf16)tile[tx][r + ty];
}

// ---------------------------------------------------------------------------
// 128x256-tile 8-wave bf16 GEMM, v3: exact grid quantization + tri-buffered
// 2-tile-lookahead pipeline.
//  - Grid: G1 = 64x12 = 768 = 3x256 CU-rounds exact; G2 = 64x4 = 256 = 1
//    round exact (the gemm256 384-block grid ran 1.5 rounds, 2nd half-idle).
//  - Per wave 64x64 out: acc[4][4] (64 VGPR) + A frags 32 + B frags 32.
//  - LDS 144 KB: A[3][128][64] + B[3][256][64], tri-buffered. Tile u lives
//    in buf u%3; stage(u+2) writes buf (u+2)%3 = (u-1)%3 whose reads
//    finished behind the barrier at top of tile u (WAR-safe).
//  - Per K-tile: vmcnt(6) -> s_barrier -> 16 ds_read_b128 -> stage(u+2)
//    (6 global_load_lds/thread) -> 32 MFMA (setprio-wrapped).
//    One barrier + one counted vmcnt per tile. FIFO audit: at top of tile
//    u outstanding = tiles u,u+1 = 12 loads; vmcnt(6) retires exactly tile
//    u; loads fly ~2 tiles (~HBM latency). vmcnt BEFORE barrier makes the
//    per-wave wait block-wide. Tail: tile 15 explicit with vmcnt(0).
//  - granule-XOR swizzle identical to the verified kernels (LDS[slot][g] =
//    global granule g^(slot&7); reads XOR with sw=c16&7): conflict-free.
// ---------------------------------------------------------------------------
template <int N, bool OUT_BF16>
__global__ __launch_bounds__(512, 1) void gemm128x256(const bf16* __restrict__ A,
                                                      const bf16* __restrict__ Bt,
                                                      const float* __restrict__ bias,
                                                      void* __restrict__ outp,
                                                      float oscale, int oscale_n) {
    constexpr int K  = 1024;
    constexpr int KT = 16;
    __shared__ __align__(16) bf16 lds[73728];   // A: [0,24576), B: [24576,73728)

    const int tid  = threadIdx.x;
    const int wv   = tid >> 6;          // 0..7
    const int lane = tid & 63;
    const int wm   = wv >> 2;           // 0..1 : M-half
    const int wn   = wv & 3;            // 0..3 : N strip base
    const int quad = lane >> 4, c16 = lane & 15;
    const int sw   = c16 & 7;

    // XCD-aware bijective remap: mIdx spread mod 8 across XCDs.
    const int lin  = (int)blockIdx.x;
    const int mIdx = (lin & 7) + 8 * ((lin >> 3) & 7);   // 0..63
    const int nIdx = lin >> 6;                           // G1: 0..11, G2: 0..3
    const int m0   = mIdx * 128;
    const int n0   = nIdx * 256;

    // Stage K-tile kt into buf kt%3: A (1 unit of 128 slots) + B (2 units).
    // 6 global_load_lds per thread. Source granule pre-swizzled: g^(slot&7).
    auto stage = [&](int kt) {
        if (kt >= KT) return;
        const int db = kt % 3;
        #pragma unroll
        for (int r = 0; r < 2; ++r) {
            const int idx  = r * 512 + tid;
            const int slot = idx >> 3;
            const int kg   = kt * 64 + (((idx & 7) ^ (slot & 7)) << 3);
            __builtin_amdgcn_global_load_lds(
                (const __attribute__((address_space(1))) void*)(A + (size_t)(m0 + slot) * K + kg),
                (__attribute__((address_space(3))) void*)(&lds[db * 8192 + (r * 8 + wv) * 512]),
                16, 0, 0);
        }
        #pragma unroll
        for (int h = 0; h < 2; ++h)
            #pragma unroll
            for (int r = 0; r < 2; ++r) {
                const int idx  = r * 512 + tid;
                const int slot = idx >> 3;
                const int kg   = kt * 64 + (((idx & 7) ^ (slot & 7)) << 3);
                __builtin_amdgcn_global_load_lds(
                    (const __attribute__((address_space(1))) void*)(Bt + (size_t)(n0 + h * 128 + slot) * K + kg),
                    (__attribute__((address_space(3))) void*)(&lds[24576 + db * 16384 + h * 8192 + (r * 8 + wv) * 512]),
                    16, 0, 0);
            }
    };

    f32x4 acc[4][4] = {};
    bf16x8 af[4][2], bfv[4][2];

    // B-frag column for nf: (nf>>1)*128 + wn*32 + (nf&1)*16 + c16
#define TILE_BODY(DB, SKT)                                                        \
    {                                                                             \
        _Pragma("unroll") for (int mq = 0; mq < 4; ++mq)                          \
            _Pragma("unroll") for (int ks = 0; ks < 2; ++ks)                      \
                af[mq][ks] = *(const bf16x8*)&lds[(DB) * 8192 +                   \
                    (wm * 64 + mq * 16 + c16) * 64 + (((ks * 4 + quad) ^ sw) << 3)]; \
        _Pragma("unroll") for (int nf = 0; nf < 4; ++nf)                          \
            _Pragma("unroll") for (int ks = 0; ks < 2; ++ks)                      \
                bfv[nf][ks] = *(const bf16x8*)&lds[24576 + (DB) * 16384 +         \
                    ((nf >> 1) * 128 + wn * 32 + (nf & 1) * 16 + c16) * 64 +      \
                    (((ks * 4 + quad) ^ sw) << 3)];                               \
        stage(SKT);                                                               \
        __builtin_amdgcn_s_setprio(1);                                            \
        _Pragma("unroll") for (int mq = 0; mq < 4; ++mq)                          \
            _Pragma("unroll") for (int nf = 0; nf < 4; ++nf)                      \
                _Pragma("unroll") for (int ks = 0; ks < 2; ++ks)                  \
                    acc[mq][nf] = MFMA16(af[mq][ks], bfv[nf][ks], acc[mq][nf]);   \
        __builtin_amdgcn_s_setprio(0);                                            \
    }
#define VMBAR(NSTR)                                                               \
    asm volatile("s_waitcnt vmcnt(" NSTR ")" ::: "memory");                       \
    __builtin_amdgcn_s_barrier();

    // Prologue: tiles 0 and 1 in flight (12 loads).
    stage(0);
    stage(1);

    // Tiles 0..14 (u=14 stages kt=16 -> no-op). Hand-unrolled x3: db const.
    #pragma unroll 1
    for (int i = 0; i < 5; ++i) {
        const int u = 3 * i;
        VMBAR("6") TILE_BODY(0, u + 2)
        VMBAR("6") TILE_BODY(1, u + 3)
        VMBAR("6") TILE_BODY(2, u + 4)
    }
    // Tile 15 (buf 0), all loads drained.
    VMBAR("0") TILE_BODY(0, KT)

#undef TILE_BODY
#undef VMBAR

    #pragma unroll
    for (int nf = 0; nf < 4; ++nf) {
        const int n = n0 + (nf >> 1) * 128 + wn * 32 + (nf & 1) * 16 + c16;
        const float bv = bias[n];
        const float sc = (n < oscale_n) ? oscale : 1.0f;
        #pragma unroll
        for (int mq = 0; mq < 4; ++mq) {
            const int rowb = m0 + wm * 64 + mq * 16 + quad * 4;
            #pragma unroll
            for (int r = 0; r < 4; ++r) {
                float val = (acc[mq][nf][r] + bv) * sc;
                if (OUT_BF16)
                    ((bf16*)outp)[(size_t)(rowb + r) * N + n] = (bf16)val;
                else
                    ((float*)outp)[(size_t)(rowb + r) * N + n] = val;
            }
        }
    }
}

// ---------------------------------------------------------------------------
// Flash-style causal attention — EXACT round-4/6 version (87.5 us, x4
// reproduced). 3-way split-K, two-phase fold, S^T=K*Q^T register P,
// swizzled Vs, unnormalized bf16 partials.
// ---------------------------------------------------------------------------
__global__ __launch_bounds__(256, 2) void attn_fwd(const bf16* __restrict__ qkv,
                                                   bf16* __restrict__ yp0,
                                                   bf16* __restrict__ yp1,
                                                   bf16* __restrict__ yp2,
                                                   float* __restrict__ lp) {
    __shared__ __align__(16) bf16 Ks2[2][4096];       // [buf][512*key8 + 64*dgrp + 8*k7 + d7]
    __shared__ __align__(16) bf16 Vs[2][64 * 64];     // [buf] V^T [d][key], granule-XOR swizzled
#if !HAVE_K16
    __shared__ __align__(16) bf16 Ps[4][32 * 72];     // fallback: [wave][q][key]
#endif

    const int x    = blockIdx.x;                      // 0..23
    const int xq   = x / 3;                           // 0..7 : q-tile pair index
    const int sgl  = x - 3 * xq;                      // 0..2 : key segment
    const int h    = blockIdx.y;
    const int bb   = blockIdx.z;
    const int tid  = threadIdx.x;
    const int w    = tid >> 6;
    const int lane = tid & 63;
    const int quad = lane >> 4, c16 = lane & 15;

    const size_t base = (size_t)(bb * T) * QKV_LD;

    const int g = tid >> 5;   // 0..7  : d-group for V staging
    const int p = tid & 31;   // 0..31 : key-pair for V staging

    auto vs_store = [&](bf16* vbuf, const bf16x8& va, const bf16x8& vb) {
        #pragma unroll
        for (int j = 0; j < 8; ++j) {
            union { bf16 hh[2]; uint32_t u; } pk;
            pk.hh[0] = va[j]; pk.hh[1] = vb[j];
            const int row = 8 * g + j;
            *(uint32_t*)&vbuf[row * 64 + (((p >> 1) ^ (row & 15)) << 2) + ((p & 1) << 1)] = pk.u;
        }
    };

    bf16* __restrict__ ydst = (sgl == 0) ? yp0 : ((sgl == 1) ? yp1 : yp2);
    float* __restrict__ ldst = lp + (size_t)sgl * Mrows * Hn;

    for (int ph = 0; ph < 2; ++ph) {
        const int qt = ph ? xq : (15 - xq);           // phase 0: heavy tile
        const int q0 = qt * 128;
        const int rowbase = q0 + w * 32;

        const int n = 2 * qt + 2;
        int f0, f1;
        if (ph == 0) { f0 = (n + 2) / 3; f1 = (n + 1) / 3; }
        else         { f0 = n / 3;       f1 = (n + 1) / 3; }
        const int start = (sgl == 0) ? 0 : ((sgl == 1) ? f0 : f0 + f1);
        const int nkt   = (sgl == 0) ? f0 : ((sgl == 1) ? f1 : n - f0 - f1);

        __syncthreads();

        {
            const int kb = start * 64;
            #pragma unroll
            for (int ii = 0; ii < 2; ++ii) {
                const int i = 2 * w + ii;
                const bf16* gp = qkv + base + (size_t)(kb + 8 * i + (lane & 7)) * QKV_LD + Cd + h * 64 + (lane >> 3) * 8;
                __builtin_amdgcn_global_load_lds(
                    (const __attribute__((address_space(1))) void*)gp,
                    (__attribute__((address_space(3))) void*)(&Ks2[0][i * 512]), 16, 0, 0);
            }
            const bf16* vp = qkv + base + (size_t)(kb + 2 * p) * QKV_LD + 2 * Cd + h * 64 + g * 8;
            bf16x8 va = *(const bf16x8*)vp;
            bf16x8 vb = *(const bf16x8*)(vp + QKV_LD);
            vs_store(Vs[0], va, vb);
        }

        bf16x8 qf[2][2];
        #pragma unroll
        for (int mb = 0; mb < 2; ++mb) {
            const bf16* qp = qkv + base + (size_t)(rowbase + 16 * mb + c16) * QKV_LD + h * 64 + quad * 8;
            qf[mb][0] = *(const bf16x8*)qp;
            qf[mb][1] = *(const bf16x8*)(qp + 32);
        }

        f32x4 yacc[2][4] = {};
        float lsum[2] = {};

        for (int j = 0; j < nkt; ++j) {
            const int cur = j & 1, nxt = cur ^ 1;
            const int k0 = (start + j) * 64;
            __syncthreads();

            bf16x8 va, vb;
            const bool more = (j + 1 < nkt);
            if (more) {
                const int kn = k0 + 64;
                #pragma unroll
                for (int ii = 0; ii < 2; ++ii) {
                    const int i = 2 * w + ii;
                    const bf16* gp = qkv + base + (size_t)(kn + 8 * i + (lane & 7)) * QKV_LD + Cd + h * 64 + (lane >> 3) * 8;
                    __builtin_amdgcn_global_load_lds(
                        (const __attribute__((address_space(1))) void*)gp,
                        (__attribute__((address_space(3))) void*)(&Ks2[nxt][i * 512]), 16, 0, 0);
                }
                const bf16* vp = qkv + base + (size_t)(kn + 2 * p) * QKV_LD + 2 * Cd + h * 64 + g * 8;
                va = *(const bf16x8*)vp;
                vb = *(const bf16x8*)(vp + QKV_LD);
            }

            if (k0 <= rowbase + 31) {
                f32x4 s[2][4] = {};
                #pragma unroll
                for (int ks = 0; ks < 2; ++ks)
                    #pragma unroll
                    for (int blk = 0; blk < 4; ++blk) {
                        const bf16x8 kf = *(const bf16x8*)
                            &Ks2[cur][(2 * blk + (c16 >> 3)) * 512 + (4 * ks + quad) * 64 + (c16 & 7) * 8];
                        #pragma unroll
                        for (int mb = 0; mb < 2; ++mb)
                            s[mb][blk] = MFMA16(kf, qf[mb][ks], s[mb][blk]);
                    }

#if HAVE_K16
                union B4 { bf16x4 v; s16x4 s; } pb[2][4];
#endif
                #pragma unroll
                for (int mb = 0; mb < 2; ++mb) {
                    const int rb = rowbase + 16 * mb;
                    const int qglob = rb + c16;
                    const bool needMask = (k0 + 63 > rb);
                    #pragma unroll
                    for (int blk = 0; blk < 4; ++blk) {
                        #pragma unroll
                        for (int r = 0; r < 4; ++r) {
                            const int key = k0 + blk * 16 + quad * 4 + r;
                            float e = s[mb][blk][r];
                            if (needMask) e = (key > qglob) ? -INFINITY : e;
                            float pv = EXP2(e);
                            lsum[mb] += pv;
#if HAVE_K16
                            pb[mb][blk].v[r] = (bf16)pv;
#else
                            Ps[w][(mb * 16 + c16) * 72 + blk * 16 + quad * 4 + r] = (bf16)pv;
#endif
                        }
                    }
                }

#if HAVE_K16
                #pragma unroll
                for (int blk = 0; blk < 4; ++blk)
                    #pragma unroll
                    for (int d16 = 0; d16 < 4; ++d16) {
                        union B4u { bf16x4 v; s16x4 s; } vf;
                        vf.v = *(const bf16x4*)
                            &Vs[cur][(d16 * 16 + c16) * 64 + ((((blk << 2) | quad) ^ c16) << 2)];
                        #pragma unroll
                        for (int mb = 0; mb < 2; ++mb)
                            yacc[mb][d16] = __builtin_amdgcn_mfma_f32_16x16x16bf16_1k(
                                vf.s, pb[mb][blk].s, yacc[mb][d16], 0, 0, 0);
                    }
#else
                asm volatile("s_waitcnt lgkmcnt(0)" ::: "memory");
                #pragma unroll
                for (int ks = 0; ks < 2; ++ks) {
                    bf16x8 pf0 = *(const bf16x8*)&Ps[w][(0 * 16 + c16) * 72 + ks * 32 + quad * 8];
                    bf16x8 pf1 = *(const bf16x8*)&Ps[w][(1 * 16 + c16) * 72 + ks * 32 + quad * 8];
                    #pragma unroll
                    for (int d16 = 0; d16 < 4; ++d16) {
                        const int row = d16 * 16 + c16;
                        const int g0 = ks * 8 + quad * 2;
                        bf16x4 lo = *(const bf16x4*)&Vs[cur][row * 64 + ((g0 ^ c16) << 2)];
                        bf16x4 hi = *(const bf16x4*)&Vs[cur][row * 64 + (((g0 + 1) ^ c16) << 2)];
                        bf16x8 vfr;
                        vfr[0] = lo[0]; vfr[1] = lo[1]; vfr[2] = lo[2]; vfr[3] = lo[3];
                        vfr[4] = hi[0]; vfr[5] = hi[1]; vfr[6] = hi[2]; vfr[7] = hi[3];
                        yacc[0][d16] = MFMA16(pf0, vfr, yacc[0][d16]);
                        yacc[1][d16] = MFMA16(pf1, vfr, yacc[1][d16]);
                    }
                }
#endif
            }

            if (more)
                vs_store(Vs[nxt], va, vb);
        }

        #pragma unroll
        for (int mb = 0; mb < 2; ++mb) {
            lsum[mb] += __shfl_xor(lsum[mb], 16);
            lsum[mb] += __shfl_xor(lsum[mb], 32);
        }

#if HAVE_K16
        #pragma unroll
        for (int mb = 0; mb < 2; ++mb) {
            const int row = rowbase + 16 * mb + c16;
            bf16* yw = ydst + (size_t)(bb * T + row) * Cd + h * 64;
            #pragma unroll
            for (int d16 = 0; d16 < 4; ++d16) {
                bf16x4 o;
                #pragma unroll
                for (int r = 0; r < 4; ++r)
                    o[r] = (bf16)(yacc[mb][d16][r]);
                *(bf16x4*)(yw + d16 * 16 + quad * 4) = o;
            }
            if (quad == 0)
                ldst[(size_t)(bb * T + row) * Hn + h] = lsum[mb];
        }
#else
        #pragma unroll
        for (int mb = 0; mb < 2; ++mb)
            #pragma unroll
            for (int r = 0; r < 4; ++r) {
                const float lsv = __shfl(lsum[mb], quad * 4 + r);
                const int row = rowbase + 16 * mb + quad * 4 + r;
                bf16* yw = ydst + (size_t)(bb * T + row) * Cd + h * 64;
                #pragma unroll
                for (int d16 = 0; d16 < 4; ++d16)
                    yw[d16 * 16 + c16] = (bf16)(yacc[mb][d16][r]);
                if (c16 == 0)
                    ldst[(size_t)(bb * T + row) * Hn + h] = lsv;
            }
#endif
    }
}

// ---------------------------------------------------------------------------
// Combine split-K partials: y = (y0 + y1 + y2) / (l0 + l1 + l2).
// ---------------------------------------------------------------------------
__global__ __launch_bounds__(256) void attn_combine(const bf16* __restrict__ yp0,
                                                    const bf16* __restrict__ yp1,
                                                    const bf16* __restrict__ yp2,
                                                    const float* __restrict__ lp,
                                                    bf16* __restrict__ y) {
    int i = (blockIdx.x * 256 + threadIdx.x) * 8;
    int row = i >> 10;          // / Cd
    int hh  = (i & 1023) >> 6;  // head
    const size_t S = (size_t)Mrows * Hn;
    const size_t li = (size_t)row * Hn + hh;
    float l = lp[li] + lp[S + li] + lp[2 * S + li];
    float inv = 1.f / l;
    bf16x8 a = *(const bf16x8*)(yp0 + i);
    bf16x8 b = *(const bf16x8*)(yp1 + i);
    bf16x8 c = *(const bf16x8*)(yp2 + i);
    bf16x8 o;
    #pragma unroll
    for (int j = 0; j < 8; ++j)
        o[j] = (bf16)(((float)a[j] + (float)b[j] + (float)c[j]) * inv);
    *(bf16x8*)(y + i) = o;
}

// ---------------------------------------------------------------------------
extern "C" void kernel_launch(void* const* d_in, const int* in_sizes, int n_in,
                              void* d_out, int out_size, void* d_ws, size_t ws_size,
                              hipStream_t stream) {
    const float* x      = (const float*)d_in[0];
    const float* W_attn = (const float*)d_in[1];
    const float* b_attn = (const float*)d_in[2];
    const float* W_proj = (const float*)d_in[3];
    const float* b_proj = (const float*)d_in[4];
    float* out = (float*)d_out;

    bf16* xb   = (bf16*)d_ws;                               // 16.8 MB (yp2 after gemm1)
    bf16* Wat  = xb  + (size_t)Mrows * Cd;                  // 6.3 MB  (lp after gemm1)
    bf16* Wpt  = Wat + (size_t)QKV_LD * Cd;                 // 2.1 MB
    bf16* qkv  = Wpt + (size_t)Cd * Cd;                     // 50.3 MB
    bf16* yb   = qkv + (size_t)Mrows * QKV_LD;              // 16.8 MB (yp0 + combined)
    bf16* yp1  = yb  + (size_t)Mrows * Cd;                  // 16.8 MB
    bf16*  yp2 = xb;                                        // 3rd split-K partial
    float* lp  = (float*)Wat;                               // 3 x Mrows x Hn = 1.57 MB

    prep<<<8192, 256, 0, stream>>>(x, W_attn, W_proj, xb, Wat, Wpt);

    // GEMM1: 768 blocks = 3 exact CU-rounds. Q cols (n < 1024) pre-scaled.
    gemm128x256<QKV_LD, true><<<dim3((Mrows / 128) * (QKV_LD / 256)), dim3(512), 0, stream>>>(
        xb, Wat, b_attn, qkv, QSCALE, Cd);

    attn_fwd<<<dim3(24, Hn, Bsz), 256, 0, stream>>>(qkv, yb, yp1, yp2, lp);
    attn_combine<<<(Mrows * Cd) / (256 * 8), 256, 0, stream>>>(yb, yp1, yp2, lp, yb);

    // GEMM2: 256 blocks = 1 exact CU-round.
    gemm128x256<Cd, false><<<dim3((Mrows / 128) * (Cd / 256)), dim3(512), 0, stream>>>(
        yb, Wpt, b_proj, out, 1.0f, 0);
}